// Round 10
// baseline (378.563 us; speedup 1.0000x reference)
//
#include <hip/hip_runtime.h>

// emb lookup -> RNN tanh(xp_t + h @ W_hh^T) over S=128 -> 5-class head.
// B=4096, S=128, D=256, VOCAB=50000. Floats f32, x int32, out f32.
//
// Phase 0: P[v] = bf16(emb[v] @ W_ih^T + b_ih + b_hh) — project the 50k TABLE.
//   One tile per block (3125 blocks): ~8 resident blocks/CU hide load/store-ack
//   latency via TLP (looped 256-block version was latency-serialized at ~90us).
// Phase 1: R10 = R6's passing structure with 512 BLOCKS x 8 ROWS (2 blocks/CU).
//   R4-R9 lesson: any xp-delivery VMEM outstanding at __syncthreads gets drained
//   (fence semantics; raw s_barrier/LDS-DMA evasions are compiler-hostile and
//   broke correctness in R7/R9). So instead hide the drain with BLOCK-LEVEL TLP:
//   two independent blocks per CU overlap each other's barrier stalls.
//   W_hh bf16 B-frags in VGPRs; h double-buffered in granule-XOR-swizzled LDS
//   (conflict-free writes); xp gathered per-step into C-layout regs, 2 steps ahead.

typedef __attribute__((ext_vector_type(8))) short bf16x8;   // 8 bf16 = 4 VGPRs
typedef __attribute__((ext_vector_type(4))) float f32x4;    // MFMA 16x16 accumulator

#define VOCAB 50000
#define LDS_STRIDE 264   // emb kernel staging only

__device__ __align__(256) unsigned short g_P[VOCAB * 256];  // 25.6 MB projected table

static __device__ __forceinline__ float bf2f(unsigned short u) {
    union { unsigned int i; float f; } v; v.i = ((unsigned int)u) << 16; return v.f;
}
static __device__ __forceinline__ unsigned short f2bf_rne(float f) {
    union { float f; unsigned int i; } v; v.f = f;
    unsigned int r = v.i + 0x7FFFu + ((v.i >> 16) & 1u);
    return (unsigned short)(r >> 16);
}
static __device__ __forceinline__ unsigned short f2bf_fast(float f) {   // round-half-up
    union { float f; unsigned int i; } v; v.f = f;
    return (unsigned short)((v.i + 0x8000u) >> 16);
}
static __device__ __forceinline__ bf16x8 cvt8(float4 a, float4 b) {
    bf16x8 r;
    r[0] = (short)f2bf_rne(a.x); r[1] = (short)f2bf_rne(a.y);
    r[2] = (short)f2bf_rne(a.z); r[3] = (short)f2bf_rne(a.w);
    r[4] = (short)f2bf_rne(b.x); r[5] = (short)f2bf_rne(b.y);
    r[6] = (short)f2bf_rne(b.z); r[7] = (short)f2bf_rne(b.w);
    return r;
}
static __device__ __forceinline__ bf16x8 load8_bf(const float* __restrict__ p) {
    return cvt8(((const float4*)p)[0], ((const float4*)p)[1]);
}
static __device__ __forceinline__ float fast_tanh(float x) {
    x = __builtin_amdgcn_fmed3f(x, -8.f, 8.f);
    float e = __expf(2.f * x);
    return __builtin_fmaf(-2.f, __builtin_amdgcn_rcpf(e + 1.f), 1.f);
}

// ---------------- Phase 0: P = bf16(emb @ W_ih^T + (b_ih + b_hh)) ----------------
__global__ __launch_bounds__(256)
void emb_proj_kernel(const float* __restrict__ emb,
                     const float* __restrict__ W_ih,
                     const float* __restrict__ b_ih,
                     const float* __restrict__ b_hh)
{
    __shared__ __align__(16) unsigned short tin [16 * LDS_STRIDE];
    __shared__ __align__(16) unsigned short tout[16 * LDS_STRIDE];
    const int tid  = threadIdx.x;
    const int lane = tid & 63;
    const int wid  = tid >> 6;
    const int n0   = wid * 64;
    const int row  = tid >> 4, seg = tid & 15;
    const int v0   = blockIdx.x * 16;   // 3125 * 16 == 50000

    // W_ih -> bf16 B-fragments (vectorized loads)
    bf16x8 wf[4][8];
    float  bias[4];
    #pragma unroll
    for (int nt = 0; nt < 4; ++nt) {
        int n = n0 + nt * 16 + (lane & 15);
        bias[nt] = b_ih[n] + b_hh[n];
        #pragma unroll
        for (int kt = 0; kt < 8; ++kt)
            wf[nt][kt] = load8_bf(W_ih + n * 256 + (lane >> 4) * 8 + kt * 32);
    }

    // stage 16 emb rows (f32 -> bf16)
    {
        const float* src = emb + (size_t)(v0 + row) * 256 + seg * 16;
        bf16x8 lo = load8_bf(src), hi = load8_bf(src + 8);
        *(bf16x8*)(&tin[row * LDS_STRIDE + seg * 16])     = lo;
        *(bf16x8*)(&tin[row * LDS_STRIDE + seg * 16 + 8]) = hi;
    }
    __syncthreads();

    f32x4 acc[4];
    #pragma unroll
    for (int nt = 0; nt < 4; ++nt) acc[nt] = (f32x4){0.f, 0.f, 0.f, 0.f};
    #pragma unroll
    for (int kt = 0; kt < 8; ++kt) {
        bf16x8 a = *(bf16x8*)(&tin[(lane & 15) * LDS_STRIDE + (lane >> 4) * 8 + kt * 32]);
        #pragma unroll
        for (int nt = 0; nt < 4; ++nt)
            acc[nt] = __builtin_amdgcn_mfma_f32_16x16x32_bf16(a, wf[nt][kt], acc[nt], 0, 0, 0);
    }
    // C/D: col = lane&15, row = quad*4 + r
    #pragma unroll
    for (int nt = 0; nt < 4; ++nt) {
        int n = n0 + nt * 16 + (lane & 15);
        #pragma unroll
        for (int r = 0; r < 4; ++r)
            tout[((lane >> 4) * 4 + r) * LDS_STRIDE + n] = f2bf_rne(acc[nt][r] + bias[nt]);
    }
    __syncthreads();
    {
        uint4 o0 = *(uint4*)(&tout[row * LDS_STRIDE + seg * 16]);
        uint4 o1 = *(uint4*)(&tout[row * LDS_STRIDE + seg * 16 + 8]);
        uint4* dst = (uint4*)(g_P + (size_t)(v0 + row) * 256 + seg * 16);
        dst[0] = o0; dst[1] = o1;
    }
}

// ---------------- Phase 1: recurrence + classifier ----------------
// 512 blocks x 8 batch rows, 512 threads (8 waves), 2 blocks/CU.
// h LDS (per 8KB buffer, 16-row layout; rows 8-15 permanently zero):
//   (row m, col c) at byte m*512 + (((c>>3)^m)<<4) + (c&7)*2.
__global__ __launch_bounds__(512, 4)
void rnn_kernel(const int* __restrict__ x,
                const float* __restrict__ W_hh,
                const float* __restrict__ W_cls,
                const float* __restrict__ b_cls,
                float* __restrict__ out)
{
    __shared__ __align__(16) unsigned short h_lds[2][16 * 256];  // 2 x 8 KB
    __shared__ __align__(16) int tok_t[128 * 8];                 // [t][row], 4 KB
    __shared__ __align__(16) float wcls_lds[5 * 256];
    __shared__ float bcls_lds[5];

    const int tid  = threadIdx.x;
    const int lane = tid & 63;
    const int wid  = tid >> 6;          // 8 waves
    const int b0   = blockIdx.x * 8;    // 512 * 8 == 4096
    const int n0   = wid * 32;          // wave's 32-col slice (2 x 16)
    const int l15  = lane & 15;
    const int quad = lane >> 4;

    // W_hh -> bf16 B-fragments, VGPR-resident all 128 steps
    bf16x8 wf[2][8];
    #pragma unroll
    for (int nt = 0; nt < 2; ++nt) {
        int n = n0 + nt * 16 + l15;
        #pragma unroll
        for (int kt = 0; kt < 8; ++kt)
            wf[nt][kt] = load8_bf(W_hh + n * 256 + quad * 8 + kt * 32);
    }

    // stage tokens transposed: tok_t[t*8 + row], rows 0..7
    if (tid < 256) {
        int row = tid & 7, tq = tid >> 3;   // tq 0..31
        int4 v = *(const int4*)(x + (size_t)(b0 + row) * 128 + tq * 4);
        tok_t[(tq * 4 + 0) * 8 + row] = v.x;
        tok_t[(tq * 4 + 1) * 8 + row] = v.y;
        tok_t[(tq * 4 + 2) * 8 + row] = v.z;
        tok_t[(tq * 4 + 3) * 8 + row] = v.w;
    }
    if (tid < 320) ((float4*)wcls_lds)[tid] = ((const float4*)W_cls)[tid];
    if (tid < 5)   bcls_lds[tid] = b_cls[tid];
    // zero BOTH h buffers (rows 8-15 must stay zero forever)
    #pragma unroll
    for (int i = 0; i < 8; ++i) ((unsigned int*)h_lds[0])[tid + i * 512] = 0;

    // loop-invariant LDS byte offsets (buf1 = +8192 imm)
    int aoff[8];   // A-frag reads from swizzled h (rows via l15; rows 8-15 are zeros)
    #pragma unroll
    for (int kt = 0; kt < 8; ++kt)
        aoff[kt] = l15 * 512 + (((quad + 4 * kt) ^ l15) << 4);
    int woff[8];   // h writes (C-layout), conflict-free; only quad<2 stores
    #pragma unroll
    for (int nt = 0; nt < 2; ++nt)
        #pragma unroll
        for (int r = 0; r < 4; ++r) {
            int row = quad * 4 + r;
            int g   = (n0 >> 3) + nt * 2 + (l15 >> 3);
            woff[nt * 4 + r] = row * 512 + ((g ^ row) << 4) + (l15 & 7) * 2;
        }

    // prologue: gather xp(t=0)->gA, xp(t=1)->gB in C-layout (rows quad*4+r < 8 only)
    unsigned int gA[8] = {0,0,0,0,0,0,0,0};
    unsigned int gB[8] = {0,0,0,0,0,0,0,0};
    if (quad < 2) {
        #pragma unroll
        for (int r = 0; r < 4; ++r) {
            const int* xr = x + (size_t)(b0 + quad * 4 + r) * 128;
            const unsigned short* p0 = g_P + (size_t)xr[0] * 256 + n0 + l15;
            const unsigned short* p1 = g_P + (size_t)xr[1] * 256 + n0 + l15;
            gA[r] = p0[0]; gA[4 + r] = p0[16];
            gB[r] = p1[0]; gB[4 + r] = p1[16];
        }
    }
    __syncthreads();

    char* const h0 = (char*)&h_lds[0][0];
    const unsigned int colByte = (unsigned int)(n0 + l15) * 2;

    auto step = [&](const char* hA, char* hW, unsigned int* g, int t) {
        // consume g as MFMA C operand (xp pre-added for free); rows>=8 lanes: 0
        f32x4 acc0, acc1;
        #pragma unroll
        for (int r = 0; r < 4; ++r) {
            acc0[r] = bf2f((unsigned short)g[r]);
            acc1[r] = bf2f((unsigned short)g[4 + r]);
        }
        // refill g for t+2 (in flight across 2 barriers)
        if (quad < 2 && t + 2 < 128) {
            int4 tk = *(const int4*)&tok_t[(t + 2) * 8 + quad * 4];
            const unsigned short* r0 = (const unsigned short*)((const char*)g_P + ((unsigned int)tk.x * 512 + colByte));
            const unsigned short* r1 = (const unsigned short*)((const char*)g_P + ((unsigned int)tk.y * 512 + colByte));
            const unsigned short* r2 = (const unsigned short*)((const char*)g_P + ((unsigned int)tk.z * 512 + colByte));
            const unsigned short* r3 = (const unsigned short*)((const char*)g_P + ((unsigned int)tk.w * 512 + colByte));
            g[0] = r0[0]; g[4] = r0[16];
            g[1] = r1[0]; g[5] = r1[16];
            g[2] = r2[0]; g[6] = r2[16];
            g[3] = r3[0]; g[7] = r3[16];
        }
        #pragma unroll
        for (int kt = 0; kt < 8; ++kt) {
            bf16x8 a = *(const bf16x8*)(hA + aoff[kt]);
            acc0 = __builtin_amdgcn_mfma_f32_16x16x32_bf16(a, wf[0][kt], acc0, 0, 0, 0);
            acc1 = __builtin_amdgcn_mfma_f32_16x16x32_bf16(a, wf[1][kt], acc1, 0, 0, 0);
        }
        if (quad < 2) {
            #pragma unroll
            for (int r = 0; r < 4; ++r) {
                *(unsigned short*)(hW + woff[r])     = f2bf_fast(fast_tanh(acc0[r]));
                *(unsigned short*)(hW + woff[4 + r]) = f2bf_fast(fast_tanh(acc1[r]));
            }
        }
    };

    #pragma unroll 1
    for (int t2 = 0; t2 < 64; ++t2) {
        step(h0,        h0 + 8192, gA, 2 * t2);      // read buf0, write buf1
        __syncthreads();
        step(h0 + 8192, h0,        gB, 2 * t2 + 1);  // read buf1, write buf0
        __syncthreads();
    }

    // final h in buf0 (rows 0-7). Classifier: 4 threads per (row,c), shuffle-reduce.
    if (tid < 160) {
        int q = tid & 3, p = tid >> 2;
        int row = p / 5, c = p - row * 5;
        float acc = 0.f;
        #pragma unroll
        for (int kk = 0; kk < 64; ++kk) {
            int k = q * 64 + kk;
            int off = row * 512 + ((((k >> 3) ^ row)) << 4) + (k & 7) * 2;
            acc += bf2f(*(const unsigned short*)(h0 + off)) * wcls_lds[c * 256 + k];
        }
        acc += __shfl_xor(acc, 1);
        acc += __shfl_xor(acc, 2);
        if (q == 0) out[(size_t)(b0 + row) * 5 + c] = acc + bcls_lds[c];
    }
}

extern "C" void kernel_launch(void* const* d_in, const int* in_sizes, int n_in,
                              void* d_out, int out_size, void* d_ws, size_t ws_size,
                              hipStream_t stream)
{
    const int*   x     = (const int*)d_in[0];
    const float* emb   = (const float*)d_in[1];
    const float* W_ih  = (const float*)d_in[2];
    const float* W_hh  = (const float*)d_in[3];
    const float* b_ih  = (const float*)d_in[4];
    const float* b_hh  = (const float*)d_in[5];
    const float* W_cls = (const float*)d_in[6];
    const float* b_cls = (const float*)d_in[7];
    float*       out   = (float*)d_out;
    (void)d_ws; (void)ws_size;

    emb_proj_kernel<<<3125, 256, 0, stream>>>(emb, W_ih, b_ih, b_hh);
    rnn_kernel<<<512, 512, 0, stream>>>(x, W_hh, W_cls, b_cls, out);
}

// Round 11
// 238.702 us; speedup vs baseline: 1.5859x; 1.5859x over previous
//
#include <hip/hip_runtime.h>

// emb lookup -> RNN tanh(xp_t + h @ W_hh^T) over S=128 -> 5-class head.
// B=4096, S=128, D=256, VOCAB=50000. Floats f32, x int32, out f32.
//
// Phase 0: P[v] = bf16(emb[v] @ W_ih^T + b_ih + b_hh) — project the 50k TABLE.
//   1024 blocks x 512 thr grid-stride (2 resident blocks/CU) — R4-R10's 256x256
//   version was 1 block/CU latency-serialized.
// Phase 1: R6's passing 256x16x512 structure (16 rows = full MFMA M; R10's 8-row
//   split doubled work, regressed). NEW: gathers BATCHED PER 4-STEP CHUNK into
//   two register banks. All 32 loads/thread issue at a chunk's first step and
//   drain at that one barrier (hidden by its compute); the other 3 barriers have
//   zero outstanding VMEM -> no vmcnt(0) drain. Loads can't cross __syncthreads,
//   but loaded REGISTERS can — that's the whole trick.

typedef __attribute__((ext_vector_type(8))) short bf16x8;   // 8 bf16 = 4 VGPRs
typedef __attribute__((ext_vector_type(4))) float f32x4;    // MFMA 16x16 accumulator

#define VOCAB 50000
#define NBLK_EMB 1024
#define LDS_STRIDE 264   // emb kernel staging only

__device__ __align__(256) unsigned short g_P[VOCAB * 256];  // 25.6 MB projected table

static __device__ __forceinline__ float bf2f(unsigned short u) {
    union { unsigned int i; float f; } v; v.i = ((unsigned int)u) << 16; return v.f;
}
static __device__ __forceinline__ unsigned short f2bf_rne(float f) {
    union { float f; unsigned int i; } v; v.f = f;
    unsigned int r = v.i + 0x7FFFu + ((v.i >> 16) & 1u);
    return (unsigned short)(r >> 16);
}
static __device__ __forceinline__ unsigned short f2bf_fast(float f) {   // round-half-up
    union { float f; unsigned int i; } v; v.f = f;
    return (unsigned short)((v.i + 0x8000u) >> 16);
}
static __device__ __forceinline__ bf16x8 cvt8(float4 a, float4 b) {
    bf16x8 r;
    r[0] = (short)f2bf_rne(a.x); r[1] = (short)f2bf_rne(a.y);
    r[2] = (short)f2bf_rne(a.z); r[3] = (short)f2bf_rne(a.w);
    r[4] = (short)f2bf_rne(b.x); r[5] = (short)f2bf_rne(b.y);
    r[6] = (short)f2bf_rne(b.z); r[7] = (short)f2bf_rne(b.w);
    return r;
}
static __device__ __forceinline__ bf16x8 load8_bf(const float* __restrict__ p) {
    return cvt8(((const float4*)p)[0], ((const float4*)p)[1]);
}
static __device__ __forceinline__ float fast_tanh(float x) {
    x = __builtin_amdgcn_fmed3f(x, -8.f, 8.f);
    float e = __expf(2.f * x);
    return __builtin_fmaf(-2.f, __builtin_amdgcn_rcpf(e + 1.f), 1.f);
}

// ---------------- Phase 0: P = bf16(emb @ W_ih^T + (b_ih + b_hh)) ----------------
__global__ __launch_bounds__(512)
void emb_proj_kernel(const float* __restrict__ emb,
                     const float* __restrict__ W_ih,
                     const float* __restrict__ b_ih,
                     const float* __restrict__ b_hh)
{
    __shared__ __align__(16) unsigned short tin [16 * LDS_STRIDE];
    __shared__ __align__(16) unsigned short tout[16 * LDS_STRIDE];
    const int tid  = threadIdx.x;
    const int lane = tid & 63;
    const int wid  = tid >> 6;          // 8 waves
    const int n0   = wid * 32;          // wave's 32-col slice (2 nt)
    const int l15  = lane & 15;
    const int quad = lane >> 4;
    const int row  = tid >> 5, seg = tid & 31;   // loader: 8 f32 per thread

    // W_ih -> bf16 B-fragments (2 nt only -> ~half the VGPRs of the 4-nt version)
    bf16x8 wf[2][8];
    float  bias[2];
    #pragma unroll
    for (int nt = 0; nt < 2; ++nt) {
        int n = n0 + nt * 16 + l15;
        bias[nt] = b_ih[n] + b_hh[n];
        #pragma unroll
        for (int kt = 0; kt < 8; ++kt)
            wf[nt][kt] = load8_bf(W_ih + n * 256 + quad * 8 + kt * 32);
    }

    int tile = blockIdx.x;
    float4 a0, a1;
    {
        const float4* s = (const float4*)(emb + ((size_t)tile * 16 + row) * 256 + seg * 8);
        a0 = s[0]; a1 = s[1];
    }

    for (; tile < 3125; tile += NBLK_EMB) {
        *(bf16x8*)(&tin[row * LDS_STRIDE + seg * 8]) = cvt8(a0, a1);
        int tn = tile + NBLK_EMB;
        if (tn < 3125) {
            const float4* s = (const float4*)(emb + ((size_t)tn * 16 + row) * 256 + seg * 8);
            a0 = s[0]; a1 = s[1];
        }
        __syncthreads();   // B1: tin visible

        f32x4 acc[2];
        acc[0] = (f32x4){0.f, 0.f, 0.f, 0.f};
        acc[1] = (f32x4){0.f, 0.f, 0.f, 0.f};
        #pragma unroll
        for (int kt = 0; kt < 8; ++kt) {
            bf16x8 a = *(bf16x8*)(&tin[l15 * LDS_STRIDE + quad * 8 + kt * 32]);
            acc[0] = __builtin_amdgcn_mfma_f32_16x16x32_bf16(a, wf[0][kt], acc[0], 0, 0, 0);
            acc[1] = __builtin_amdgcn_mfma_f32_16x16x32_bf16(a, wf[1][kt], acc[1], 0, 0, 0);
        }
        // C/D: col = l15, row = quad*4 + r
        #pragma unroll
        for (int nt = 0; nt < 2; ++nt) {
            int n = n0 + nt * 16 + l15;
            #pragma unroll
            for (int r = 0; r < 4; ++r)
                tout[(quad * 4 + r) * LDS_STRIDE + n] = f2bf_rne(acc[nt][r] + bias[nt]);
        }
        __syncthreads();   // B2: tout complete, tin reads complete
        {
            uint4 o = *(uint4*)(&tout[row * LDS_STRIDE + seg * 8]);
            *(uint4*)(g_P + ((size_t)tile * 16 + row) * 256 + seg * 8) = o;
        }
    }
}

// ---------------- Phase 1: recurrence + classifier ----------------
// 256 blocks x 16 rows x 512 thr (8 waves). h LDS (per 8KB buffer):
//   (row m, col c) at byte m*512 + (((c>>3)^m)<<4) + (c&7)*2  (conflict-free writes).
__global__ __launch_bounds__(512, 2)
void rnn_kernel(const int* __restrict__ x,
                const float* __restrict__ W_hh,
                const float* __restrict__ W_cls,
                const float* __restrict__ b_cls,
                float* __restrict__ out)
{
    __shared__ __align__(16) unsigned short h_lds[2][16 * 256];  // 2 x 8 KB
    __shared__ __align__(16) int tok_t[128 * 16];                // [t][row]
    __shared__ __align__(16) float wcls_lds[5 * 256];
    __shared__ float bcls_lds[5];

    const int tid  = threadIdx.x;
    const int lane = tid & 63;
    const int wid  = tid >> 6;          // 8 waves
    const int b0   = blockIdx.x * 16;
    const int n0   = wid * 32;
    const int l15  = lane & 15;
    const int quad = lane >> 4;

    // W_hh -> bf16 B-fragments, VGPR-resident
    bf16x8 wf[2][8];
    #pragma unroll
    for (int nt = 0; nt < 2; ++nt) {
        int n = n0 + nt * 16 + l15;
        #pragma unroll
        for (int kt = 0; kt < 8; ++kt)
            wf[nt][kt] = load8_bf(W_hh + n * 256 + quad * 8 + kt * 32);
    }

    // stage tokens transposed: tok_t[t*16 + row]
    {
        int row = tid & 15, tq = tid >> 4;
        int4 v = *(const int4*)(x + (size_t)(b0 + row) * 128 + tq * 4);
        tok_t[(tq * 4 + 0) * 16 + row] = v.x;
        tok_t[(tq * 4 + 1) * 16 + row] = v.y;
        tok_t[(tq * 4 + 2) * 16 + row] = v.z;
        tok_t[(tq * 4 + 3) * 16 + row] = v.w;
    }
    if (tid < 320) ((float4*)wcls_lds)[tid] = ((const float4*)W_cls)[tid];
    if (tid < 5)   bcls_lds[tid] = b_cls[tid];
    #pragma unroll
    for (int i = 0; i < 4; ++i) ((unsigned int*)h_lds[0])[tid + i * 512] = 0;

    // loop-invariant LDS byte offsets (buf1 = +8192 imm)
    int aoff[8];
    #pragma unroll
    for (int kt = 0; kt < 8; ++kt)
        aoff[kt] = l15 * 512 + (((quad + 4 * kt) ^ l15) << 4);
    int woff[8];
    #pragma unroll
    for (int nt = 0; nt < 2; ++nt)
        #pragma unroll
        for (int r = 0; r < 4; ++r) {
            int row = quad * 4 + r;
            int g   = (n0 >> 3) + nt * 2 + (l15 >> 3);
            woff[nt * 4 + r] = row * 512 + ((g ^ row) << 4) + (l15 & 7) * 2;
        }

    const unsigned int colByte = (unsigned int)(n0 + l15) * 2;

    // Two register gather banks: gb[bank][p][slot], slot = {r: acc0} {4+r: acc1}
    unsigned int gb[2][4][8];

    // prologue: chunk 0 (t=0..3) into bank 0, straight from x (tok_t not ready yet)
    #pragma unroll
    for (int p = 0; p < 4; ++p)
        #pragma unroll
        for (int j = 0; j < 4; ++j) {
            int tok = x[(size_t)(b0 + quad * 4 + j) * 128 + p];
            const unsigned short* pp = g_P + (size_t)tok * 256 + n0 + l15;
            gb[0][p][j] = pp[0]; gb[0][p][4 + j] = pp[16];
        }
    __syncthreads();

    char* const h0 = (char*)&h_lds[0][0];

    // issue all 32 gather loads for chunk at tbase into bank b (constant args!)
    auto issue_chunk = [&](int b, int tbase) {
        #pragma unroll
        for (int p = 0; p < 4; ++p) {
            int4 tk = *(const int4*)&tok_t[(tbase + p) * 16 + quad * 4];
            const unsigned short* r0 = (const unsigned short*)((const char*)g_P + ((unsigned int)tk.x * 512 + colByte));
            const unsigned short* r1 = (const unsigned short*)((const char*)g_P + ((unsigned int)tk.y * 512 + colByte));
            const unsigned short* r2 = (const unsigned short*)((const char*)g_P + ((unsigned int)tk.z * 512 + colByte));
            const unsigned short* r3 = (const unsigned short*)((const char*)g_P + ((unsigned int)tk.w * 512 + colByte));
            gb[b][p][0] = r0[0]; gb[b][p][4] = r0[16];
            gb[b][p][1] = r1[0]; gb[b][p][5] = r1[16];
            gb[b][p][2] = r2[0]; gb[b][p][6] = r2[16];
            gb[b][p][3] = r3[0]; gb[b][p][7] = r3[16];
        }
    };

    auto stepf = [&](const char* hA, char* hW, int b, int p) {
        f32x4 acc0, acc1;
        #pragma unroll
        for (int r = 0; r < 4; ++r) {
            acc0[r] = bf2f((unsigned short)gb[b][p][r]);
            acc1[r] = bf2f((unsigned short)gb[b][p][4 + r]);
        }
        #pragma unroll
        for (int kt = 0; kt < 8; ++kt) {
            bf16x8 a = *(const bf16x8*)(hA + aoff[kt]);
            acc0 = __builtin_amdgcn_mfma_f32_16x16x32_bf16(a, wf[0][kt], acc0, 0, 0, 0);
            acc1 = __builtin_amdgcn_mfma_f32_16x16x32_bf16(a, wf[1][kt], acc1, 0, 0, 0);
        }
        #pragma unroll
        for (int r = 0; r < 4; ++r) {
            *(unsigned short*)(hW + woff[r])     = f2bf_fast(fast_tanh(acc0[r]));
            *(unsigned short*)(hW + woff[4 + r]) = f2bf_fast(fast_tanh(acc1[r]));
        }
    };

    #pragma unroll 1
    for (int i8 = 0; i8 < 16; ++i8) {
        const int tb = i8 * 8;
        // chunk A (steps tb..tb+3) from bank0; issue chunk B into bank1 now —
        // these loads drain at the FIRST barrier below (hidden), banks cross the
        // rest in registers.
        issue_chunk(1, tb + 4);
        stepf(h0,        h0 + 8192, 0, 0); __syncthreads();
        stepf(h0 + 8192, h0,        0, 1); __syncthreads();
        stepf(h0,        h0 + 8192, 0, 2); __syncthreads();
        stepf(h0 + 8192, h0,        0, 3); __syncthreads();
        // chunk B (steps tb+4..tb+7) from bank1; refill bank0 for next iteration
        if (i8 < 15) issue_chunk(0, tb + 8);
        stepf(h0,        h0 + 8192, 1, 0); __syncthreads();
        stepf(h0 + 8192, h0,        1, 1); __syncthreads();
        stepf(h0,        h0 + 8192, 1, 2); __syncthreads();
        stepf(h0 + 8192, h0,        1, 3); __syncthreads();
    }

    // final h in buf0 (t=127 wrote buf0). Classifier: 4 threads per (row,c).
    if (tid < 320) {
        int q = tid & 3, p = tid >> 2;
        int row = p / 5, c = p - row * 5;
        float acc = 0.f;
        #pragma unroll
        for (int kk = 0; kk < 64; ++kk) {
            int k = q * 64 + kk;
            int off = row * 512 + ((((k >> 3) ^ row)) << 4) + (k & 7) * 2;
            acc += bf2f(*(const unsigned short*)(h0 + off)) * wcls_lds[c * 256 + k];
        }
        acc += __shfl_xor(acc, 1);
        acc += __shfl_xor(acc, 2);
        if (q == 0) out[(size_t)(b0 + row) * 5 + c] = acc + bcls_lds[c];
    }
}

extern "C" void kernel_launch(void* const* d_in, const int* in_sizes, int n_in,
                              void* d_out, int out_size, void* d_ws, size_t ws_size,
                              hipStream_t stream)
{
    const int*   x     = (const int*)d_in[0];
    const float* emb   = (const float*)d_in[1];
    const float* W_ih  = (const float*)d_in[2];
    const float* W_hh  = (const float*)d_in[3];
    const float* b_ih  = (const float*)d_in[4];
    const float* b_hh  = (const float*)d_in[5];
    const float* W_cls = (const float*)d_in[6];
    const float* b_cls = (const float*)d_in[7];
    float*       out   = (float*)d_out;
    (void)d_ws; (void)ws_size;

    emb_proj_kernel<<<NBLK_EMB, 512, 0, stream>>>(emb, W_ih, b_ih, b_hh);
    rnn_kernel<<<256, 512, 0, stream>>>(x, W_hh, W_cls, b_cls, out);
}